// Round 6
// baseline (261.525 us; speedup 1.0000x reference)
//
#include <hip/hip_runtime.h>

// AGCRNCell on gfx950.  B=32, N=2048, C=66, CHEB_K=3, F=2112 (= 33*64, exact).
// R15b: identical to R15 (round-5 bench was an infra failure, not a kernel
//      failure; re-audit found no hazards). Changes vs R14:
//  (1) epi0/epi1 G-writes via LDS transpose (acc -> swizzled 128x64 LDS in As[0],
//      one __syncthreads, contiguous bf16x8 row stores). Fixes the 32B-granule
//      scatter (partial-line RMW refetch + 32 scattered stores/lane tail).
//  (2) gemm_w: z*state tile through the same LDS transpose; full 72-elem Gu rows
//      (x | z*state | pads) written as 9 aligned 16B stores; side section gone.
//      Gu secs 1/2 x-cols copied from Gg (gate/update cats share x).
//  (3) update phase packed to C=2048 (cmode=1): Tu = 64-row sections in T0's
//      buffer, GEMM3/4 grids 528->512 (-3% work), G-scatter offset +2.
//  Kept: W-fold, fused prologue, single-pass gate W-GEMM, 128x64 big-GEMM core.

typedef __bf16 bf16x8 __attribute__((ext_vector_type(8)));
typedef __bf16 bf16x4 __attribute__((ext_vector_type(4)));
typedef __bf16 bf16x2 __attribute__((ext_vector_type(2)));
typedef float  f32x4  __attribute__((ext_vector_type(4)));

#define GLB(p) ((__attribute__((address_space(1))) void*)(void*)(p))
#define LDS(p) ((__attribute__((address_space(3))) void*)(p))

// ---- fused prologue ----
// blocks [0,2048):     S[n][m] = softmax_m(relu(E[n]·E[m]))
// blocks [2048,2176):  WTg[o][k] folded: jj0 -> W0-W2, jj1 -> W1, jj2 -> 2*W2
// blocks [2176,2304):  WTu[o][k] folded likewise (rows 64..127 zero)
// blocks [2304,2816):  build gate-cat: T0[f][n] + G_gate sec0  (cat = [x,state])
__global__ __launch_bounds__(256, 2)
void prologue_kernel(const float* __restrict__ E, __bf16* __restrict__ S,
                     const float* __restrict__ Wg, __bf16* __restrict__ WTg,
                     const float* __restrict__ Wu, __bf16* __restrict__ WTu,
                     const float* __restrict__ x, const float* __restrict__ st,
                     __bf16* __restrict__ T, __bf16* __restrict__ G) {
    const int bid = blockIdx.x;
    const int t = threadIdx.x;            // 256
    __shared__ float Ls[66 * 129];        // 34 KB (build branch; [0..7] reused as red)
    if (bid >= 2304) {
        // ---- build gate-cat branch ----
        const int rb = bid - 2304;
        const int b  = rb >> 4;
        const int n0 = (rb & 15) << 7;
        const size_t mb = (size_t)b * 2048 + n0;
        if (t < 128) {
            const float2 v = *(const float2*)&x[(mb + t) * 2];
            Ls[t] = v.x;
            Ls[129 + t] = v.y;
        }
#pragma unroll
        for (int r = 0; r < 8; ++r) {        // 128 rows x 16 col-quads
            const int task = r * 256 + t;
            const int q = task & 15, n = task >> 4;
            f32x4 v = *(const f32x4*)&st[(mb + n) * 64 + q * 4];
            const int base = (2 + q * 4) * 129 + n;
#pragma unroll
            for (int j = 0; j < 4; ++j) Ls[base + j * 129] = v[j];
        }
        __syncthreads();
        // T-layout store: coalesced columns
#pragma unroll
        for (int r = 0; r < 5; ++r) {        // 66 c x 16 segs = 1056 tasks
            const int task = r * 256 + t;
            if (task < 1056) {
                const int c = task >> 4, seg = task & 15;
                const float* src = &Ls[c * 129 + seg * 8];
                bf16x8 o;
#pragma unroll
                for (int j = 0; j < 8; ++j) o[j] = (__bf16)src[j];
                *(bf16x8*)&T[(size_t)(b * 66 + c) * 2048 + n0 + seg * 8] = o;
            }
        }
        // G section 0: row (b, n0+n), k = cc in [0,66), octets 0..8 (cc>=66 -> 0)
        {
            const int n = t & 127, half = t >> 7;
            const size_t grow = ((size_t)(b * 2048 + n0 + n)) * 256;
            for (int oct = half * 5; oct < (half ? 9 : 5); ++oct) {
                bf16x8 o8;
#pragma unroll
                for (int j = 0; j < 8; ++j) {
                    const int cc = oct * 8 + j;
                    o8[j] = (cc < 66) ? (__bf16)Ls[cc * 129 + n] : (__bf16)0.f;
                }
                *(bf16x8*)&G[grow + oct * 8] = o8;
            }
        }
        return;
    }
    if (bid >= 2048) {
        // ---- folded weight-transpose branch ----
        const float* W = (bid < 2176) ? Wg : Wu;
        __bf16* WT = (bid < 2176) ? WTg : WTu;
        const int Nout = (bid < 2176) ? 128 : 64;
        const int id = (bid - ((bid < 2176) ? 2048 : 2176)) * 256 + t;  // 128*256
        const int o = id >> 8, k = id & 255;
        const int jj = (k >= 144) ? 2 : (k >= 72 ? 1 : 0);
        const int cc = k - 72 * jj;
        const bool ok = (o < Nout) && (cc < 66) && (k < 216);
        float v = 0.f;
        if (ok) {
            if (jj == 0)      v = W[(size_t)cc * Nout + o] - W[(size_t)(132 + cc) * Nout + o];
            else if (jj == 1) v = W[(size_t)(66 + cc) * Nout + o];
            else              v = 2.f * W[(size_t)(132 + cc) * Nout + o];
        }
        WT[id] = (__bf16)v;
        return;
    }
    // ---- adaptive-adjacency softmax branch ----
    const int n = bid;
    const int l = t & 63, w = t >> 6;
    float* sm = Ls;           // [0..3]
    float* ss = Ls + 4;       // [4..7]
    float en[10];
#pragma unroll
    for (int i = 0; i < 10; ++i) en[i] = E[n * 10 + i];
    float vals[8];
    float mx = 0.f;
#pragma unroll
    for (int q = 0; q < 8; ++q) {
        const int m = q * 256 + t;
        const float* em = E + (size_t)m * 10;
        float d = 0.f;
#pragma unroll
        for (int i = 0; i < 10; ++i) d += en[i] * em[i];
        d = fmaxf(d, 0.f);
        vals[q] = d;
        mx = fmaxf(mx, d);
    }
#pragma unroll
    for (int off = 32; off; off >>= 1) mx = fmaxf(mx, __shfl_xor(mx, off));
    if (l == 0) sm[w] = mx;
    __syncthreads();
    mx = fmaxf(fmaxf(sm[0], sm[1]), fmaxf(sm[2], sm[3]));
    float sum = 0.f;
#pragma unroll
    for (int q = 0; q < 8; ++q) { vals[q] = __expf(vals[q] - mx); sum += vals[q]; }
#pragma unroll
    for (int off = 32; off; off >>= 1) sum += __shfl_xor(sum, off);
    if (l == 0) ss[w] = sum;
    __syncthreads();
    sum = ss[0] + ss[1] + ss[2] + ss[3];
    const float inv = 1.f / sum;
#pragma unroll
    for (int q = 0; q < 8; ++q) S[(size_t)n * 2048 + q * 256 + t] = (__bf16)(vals[q] * inv);
}

// ---------------- pipelined GEMM: out[M][C] = A[M][K] @ Bt[C][K]^T ----------------
// 256 thr = 4 waves (2m x 2c), tile 128m x 64c, wave-tile 64x32 (4x2 frags), BK=64.
// Double-buffered LDS (48 KB -> 3 blocks/CU); per iter: stage next buf ->
// s_waitcnt vmcnt(6) -> raw s_barrier -> compute -> raw s_barrier. XOR-granule
// swizzle: conflict-free ds_read_b128. swz=1: mt = id&15, ct = id>>4.
// cmode: 0 -> c maps (b=c/66, cc=c-66b, gcol=gsec+cc);  1 -> packed 64-col
//        batches (b=c>>6, gcol=gsec+2+(c&63)).
// epi: 0 outT[c][m]=bf16(acc) + G rows via LDS transpose
//      1 G rows only (gsec=144)                         [W-fold: plain S^2x]
//      3 (c<64) outF[m*64+c] = r*state+(1-r)*tanh(acc+bias[c]), r=zrI[m*64+c]
__global__ __launch_bounds__(256, 3)
void gemm_pipe(const __bf16* __restrict__ A, int lda,
               const __bf16* __restrict__ Bt, int ldb,
               int K, int epi, int swz, int cmode,
               __bf16* __restrict__ outT,
               float* __restrict__ outF, const float* __restrict__ bias,
               const __bf16* __restrict__ zrI,
               const float* __restrict__ state,
               __bf16* __restrict__ Gout, int gsec) {
    __shared__ __align__(16) __bf16 As[2][128 * 64];   // 32 KB
    __shared__ __align__(16) __bf16 Bs[2][64 * 64];    // 16 KB
    int mt, ct;
    if (swz) { mt = blockIdx.x & 15; ct = blockIdx.x >> 4; }
    else     { mt = blockIdx.x;      ct = blockIdx.y; }
    const int m0 = mt * 128, c0 = ct * 64;
    const int t = threadIdx.x;
    const int l = t & 63, w = t >> 6;
    const int wr = w >> 1, wc = w & 1;
    const int lm = l & 15, kq = l >> 4, lm7 = lm & 7;
    const int sr = l >> 3;               // row-within-chunk
    const int gsw = (l & 7) ^ sr;        // swizzled source granule

    f32x4 acc[4][2];
#pragma unroll
    for (int i = 0; i < 4; ++i)
#pragma unroll
        for (int j = 0; j < 2; ++j) acc[i][j] = (f32x4)0.f;

    const __bf16* Asrc = A  + (size_t)(m0 + w * 8 + sr) * lda + gsw * 8;
    const __bf16* Bsrc = Bt + (size_t)(c0 + w * 8 + sr) * ldb + gsw * 8;
    const int dstA = w * 512 + l * 8;

    auto stage = [&](int buf, int k0) {
#pragma unroll
        for (int q = 0; q < 4; ++q)
            __builtin_amdgcn_global_load_lds(GLB(Asrc + (size_t)q * 32 * lda + k0),
                                             LDS(&As[buf][q * 2048 + dstA]), 16, 0, 0);
#pragma unroll
        for (int q = 0; q < 2; ++q)
            __builtin_amdgcn_global_load_lds(GLB(Bsrc + (size_t)q * 32 * ldb + k0),
                                             LDS(&Bs[buf][q * 2048 + dstA]), 16, 0, 0);
    };
    auto compute = [&](int buf) {
        const __bf16* Ab = &As[buf][0];
        const __bf16* Bb = &Bs[buf][0];
#pragma unroll
        for (int ks = 0; ks < 2; ++ks) {
            const int ga = (((ks << 2) | kq) ^ lm7) << 3;
            bf16x8 af[4], bfr[2];
#pragma unroll
            for (int i = 0; i < 4; ++i)
                af[i] = *(const bf16x8*)&Ab[(wr * 64 + i * 16 + lm) * 64 + ga];
#pragma unroll
            for (int j = 0; j < 2; ++j)
                bfr[j] = *(const bf16x8*)&Bb[(wc * 32 + j * 16 + lm) * 64 + ga];
#pragma unroll
            for (int i = 0; i < 4; ++i)
#pragma unroll
                for (int j = 0; j < 2; ++j)
                    acc[i][j] = __builtin_amdgcn_mfma_f32_16x16x32_bf16(af[i], bfr[j], acc[i][j], 0, 0, 0);
        }
    };

    stage(0, 0);
    const int iters = K >> 6;            // even (32 big / 4 W)
    for (int i = 0; i + 2 <= iters; i += 2) {
        stage(1, (i + 1) << 6);
        __builtin_amdgcn_sched_barrier(0);
        __builtin_amdgcn_s_waitcnt(0x0F76);      // vmcnt(6): own buf0 loads done
        __builtin_amdgcn_s_barrier();
        __builtin_amdgcn_sched_barrier(0);
        compute(0);
        __builtin_amdgcn_sched_barrier(0);
        __builtin_amdgcn_s_barrier();            // buf0 free for restage
        __builtin_amdgcn_sched_barrier(0);
        if (i + 2 < iters) {
            stage(0, (i + 2) << 6);
            __builtin_amdgcn_sched_barrier(0);
            __builtin_amdgcn_s_waitcnt(0x0F76);  // vmcnt(6): own buf1 loads done
        } else {
            __builtin_amdgcn_s_waitcnt(0x0F70);  // vmcnt(0)
        }
        __builtin_amdgcn_s_barrier();
        __builtin_amdgcn_sched_barrier(0);
        compute(1);
        __builtin_amdgcn_sched_barrier(0);
        if (i + 4 <= iters) {
            __builtin_amdgcn_s_barrier();        // buf1 free for restage
            __builtin_amdgcn_sched_barrier(0);
        }
    }

    // epilogue: C row = m (quad*4+reg), col = lane&15  [verified m89 layout]
    const int rb0 = m0 + wr * 64 + kq * 4;
    const int cb0 = c0 + wc * 32 + lm;
    __bf16* Lt = &As[0][0];              // buf0: free after last compute(1)
#pragma unroll
    for (int i = 0; i < 4; ++i) {
        const int rbase = rb0 + i * 16;
#pragma unroll
        for (int j = 0; j < 2; ++j) {
            const int c = cb0 + j * 16;
            f32x4 v = acc[i][j];
            if (epi <= 1) {
                bf16x4 pk;
#pragma unroll
                for (int r = 0; r < 4; ++r) pk[r] = (__bf16)v[r];
                if (epi == 0)
                    *(bf16x4*)&outT[(size_t)c * 2048 + rbase] = pk;
                // stash into swizzled LDS [128][64] for the G row pass
                const int mbL = wr * 64 + kq * 4 + i * 16;
                const int clocb = wc * 32 + lm + j * 16;
#pragma unroll
                for (int r = 0; r < 4; ++r) {
                    const int ml = mbL + r;
                    const int swr = (ml & 7) ^ ((ml >> 3) & 7);
                    Lt[ml * 64 + ((((clocb >> 3) ^ swr) & 7) << 3) + (clocb & 7)] = pk[r];
                }
            } else {
                if (c < 64) {
                    const float bb = bias[c];
#pragma unroll
                    for (int r = 0; r < 4; ++r) {
                        const int m = rbase + r;
                        float xx = fminf(fmaxf(v[r] + bb, -15.f), 15.f);
                        float e = __expf(2.f * xx);
                        float hc = (e - 1.f) / (e + 1.f);
                        float rr = (float)zrI[(size_t)m * 64 + c];
                        float s = state[(size_t)m * 64 + c];
                        outF[(size_t)m * 64 + c] = rr * s + (1.f - rr) * hc;
                    }
                }
            }
        }
    }
    if (epi <= 1) {
        __syncthreads();
        // G row pass: thread = (row mloc, half h); contiguous bf16x8 runs.
        const int mloc = t >> 1, h = t & 1;
        const int m = m0 + mloc;
        const int sw = (mloc & 7) ^ ((mloc >> 3) & 7);
#pragma unroll
        for (int k = 0; k < 4; ++k) {
            const int g = h * 4 + k;
            const bf16x8 v = *(const bf16x8*)&Lt[mloc * 64 + ((g ^ sw) & 7) * 8];
            const int c = c0 + g * 8;
            if (cmode) {
                const int b = c >> 6;
                *(bf16x8*)&Gout[((size_t)(b * 2048 + m)) * 256 + gsec + 2 + (c & 63)] = v;
            } else {
                const int b0 = c / 66, b7 = (c + 7) / 66;
                if (b0 == b7) {
                    *(bf16x8*)&Gout[((size_t)(b0 * 2048 + m)) * 256 + gsec + (c - b0 * 66)] = v;
                } else {
#pragma unroll
                    for (int e = 0; e < 8; ++e) {
                        const int ce = c + e, be = ce / 66;
                        Gout[((size_t)(be * 2048 + m)) * 256 + gsec + (ce - be * 66)] = v[e];
                    }
                }
            }
        }
    }
}

// ---------------- wide W-GEMM (gate only): out[M][128] = A[M][256] @ Bt[128][256]^T
// tile 128m x 128c, 4 waves (2x2), wave-tile 64x64 (4x4 frags), BK=64, K=256.
// 64 KB LDS dbuf -> 2 blocks/CU; grid 512 (one c-pass: G fetched ONCE).
// epi: c<64 -> z=sigmoid(acc+bias[c]); z*state -> Tu[b*64+c][n] (8B reg stores)
//      and into swizzled LDS; c>=64 -> ZR[m*64+c-64]=sigmoid.
// Row pass: Gu rows [0..72) = [x | z*state | 0] as 9 aligned 16B stores;
//           Gu x-cols of secs 1/2 copied from A (= Gg, identical by algebra).
__global__ __launch_bounds__(256, 2)
void gemm_w(const __bf16* __restrict__ A,
            const __bf16* __restrict__ Bt,
            __bf16* __restrict__ outT, const float* __restrict__ bias,
            __bf16* __restrict__ zrO,
            const float* __restrict__ state,
            __bf16* __restrict__ Gout,
            const float* __restrict__ xin) {
    __shared__ __align__(16) __bf16 As[2][128 * 64];   // 32 KB
    __shared__ __align__(16) __bf16 Bs[2][128 * 64];   // 32 KB
    const int m0 = blockIdx.x * 128;
    const int t = threadIdx.x;
    const int l = t & 63, w = t >> 6;
    const int wr = w >> 1, wc = w & 1;
    const int lm = l & 15, kq = l >> 4, lm7 = lm & 7;
    const int sr = l >> 3;
    const int gsw = (l & 7) ^ sr;

    f32x4 acc[4][4];
#pragma unroll
    for (int i = 0; i < 4; ++i)
#pragma unroll
        for (int j = 0; j < 4; ++j) acc[i][j] = (f32x4)0.f;

    const __bf16* Asrc = A  + (size_t)(m0 + w * 8 + sr) * 256 + gsw * 8;
    const __bf16* Bsrc = Bt + (size_t)(w * 8 + sr) * 256 + gsw * 8;
    const int dstA = w * 512 + l * 8;

    auto stage = [&](int buf, int k0) {
#pragma unroll
        for (int q = 0; q < 4; ++q)
            __builtin_amdgcn_global_load_lds(GLB(Asrc + (size_t)q * 32 * 256 + k0),
                                             LDS(&As[buf][q * 2048 + dstA]), 16, 0, 0);
#pragma unroll
        for (int q = 0; q < 4; ++q)
            __builtin_amdgcn_global_load_lds(GLB(Bsrc + (size_t)q * 32 * 256 + k0),
                                             LDS(&Bs[buf][q * 2048 + dstA]), 16, 0, 0);
    };
    auto compute = [&](int buf) {
        const __bf16* Ab = &As[buf][0];
        const __bf16* Bb = &Bs[buf][0];
#pragma unroll
        for (int ks = 0; ks < 2; ++ks) {
            const int ga = (((ks << 2) | kq) ^ lm7) << 3;
            bf16x8 af[4], bfr[4];
#pragma unroll
            for (int i = 0; i < 4; ++i)
                af[i] = *(const bf16x8*)&Ab[(wr * 64 + i * 16 + lm) * 64 + ga];
#pragma unroll
            for (int j = 0; j < 4; ++j)
                bfr[j] = *(const bf16x8*)&Bb[(wc * 64 + j * 16 + lm) * 64 + ga];
#pragma unroll
            for (int i = 0; i < 4; ++i)
#pragma unroll
                for (int j = 0; j < 4; ++j)
                    acc[i][j] = __builtin_amdgcn_mfma_f32_16x16x32_bf16(af[i], bfr[j], acc[i][j], 0, 0, 0);
        }
    };

    stage(0, 0);
    const int iters = 4;                 // K=256, BK=64
    for (int i = 0; i + 2 <= iters; i += 2) {
        stage(1, (i + 1) << 6);
        __builtin_amdgcn_sched_barrier(0);
        __builtin_amdgcn_s_waitcnt(0x0F78);      // vmcnt(8): own buf0 loads done
        __builtin_amdgcn_s_barrier();
        __builtin_amdgcn_sched_barrier(0);
        compute(0);
        __builtin_amdgcn_sched_barrier(0);
        __builtin_amdgcn_s_barrier();            // buf0 free for restage
        __builtin_amdgcn_sched_barrier(0);
        if (i + 2 < iters) {
            stage(0, (i + 2) << 6);
            __builtin_amdgcn_sched_barrier(0);
            __builtin_amdgcn_s_waitcnt(0x0F78);  // vmcnt(8): own buf1 loads done
        } else {
            __builtin_amdgcn_s_waitcnt(0x0F70);  // vmcnt(0)
        }
        __builtin_amdgcn_s_barrier();
        __builtin_amdgcn_sched_barrier(0);
        compute(1);
        __builtin_amdgcn_sched_barrier(0);
        if (i + 4 <= iters) {
            __builtin_amdgcn_s_barrier();        // barrier before buf1 restage
            __builtin_amdgcn_sched_barrier(0);
        }
    }

    const int rb0 = m0 + wr * 64 + kq * 4;
    const int cb0 = wc * 64 + lm;
    __bf16* Lt = &As[0][0];              // buf0: free after last compute(1)
#pragma unroll
    for (int i = 0; i < 4; ++i) {
        const int rbase = rb0 + i * 16;
#pragma unroll
        for (int j = 0; j < 4; ++j) {
            const int c = cb0 + j * 16;
            f32x4 v = acc[i][j];
            const float bb = bias[c];
            if (c < 64) {
                // z*state -> Tu row b*64+c (packed sections) + swizzled LDS
                const int b = rbase >> 11, n = rbase & 2047;
                bf16x4 pk;
#pragma unroll
                for (int r = 0; r < 4; ++r) {
                    float xx = fminf(fmaxf(v[r] + bb, -30.f), 30.f);
                    const float z = 1.f / (1.f + __expf(-xx));
                    const float sv = state[(size_t)(rbase + r) * 64 + c];
                    pk[r] = (__bf16)(z * sv);
                }
                *(bf16x4*)&outT[(size_t)(b * 64 + c) * 2048 + n] = pk;
                const int mbL = wr * 64 + kq * 4 + i * 16;
#pragma unroll
                for (int r = 0; r < 4; ++r) {
                    const int ml = mbL + r;
                    const int swr = (ml & 7) ^ ((ml >> 3) & 7);
                    Lt[ml * 64 + ((((c >> 3) ^ swr) & 7) << 3) + (c & 7)] = pk[r];
                }
            } else {
#pragma unroll
                for (int r = 0; r < 4; ++r) {
                    float xx = fminf(fmaxf(v[r] + bb, -30.f), 30.f);
                    zrO[(size_t)(rbase + r) * 64 + (c - 64)] = (__bf16)(1.f / (1.f + __expf(-xx)));
                }
            }
        }
    }
    __syncthreads();
    // Gu row pass: full update-cat rows [0..72) + x-col copies for secs 1/2
    {
        const int mloc = t >> 1, h = t & 1;
        const int m = m0 + mloc;
        const int sw = (mloc & 7) ^ ((mloc >> 3) & 7);
        const size_t gr = (size_t)m * 256;
        auto ldg = [&](int g) { return *(const bf16x8*)&Lt[mloc * 64 + ((g ^ sw) & 7) * 8]; };
        if (h == 0) {
            const float2 vx = *(const float2*)&xin[(size_t)m * 2];
            const bf16x8 g0 = ldg(0), g1 = ldg(1), g2 = ldg(2), g3 = ldg(3), g4 = ldg(4);
            bf16x8 o;
            o[0] = (__bf16)vx.x; o[1] = (__bf16)vx.y;
#pragma unroll
            for (int e = 0; e < 6; ++e) o[2 + e] = g0[e];
            *(bf16x8*)&Gout[gr + 0] = o;
            o[0] = g0[6]; o[1] = g0[7];
#pragma unroll
            for (int e = 0; e < 6; ++e) o[2 + e] = g1[e];
            *(bf16x8*)&Gout[gr + 8] = o;
            o[0] = g1[6]; o[1] = g1[7];
#pragma unroll
            for (int e = 0; e < 6; ++e) o[2 + e] = g2[e];
            *(bf16x8*)&Gout[gr + 16] = o;
            o[0] = g2[6]; o[1] = g2[7];
#pragma unroll
            for (int e = 0; e < 6; ++e) o[2 + e] = g3[e];
            *(bf16x8*)&Gout[gr + 24] = o;
            o[0] = g3[6]; o[1] = g3[7];
#pragma unroll
            for (int e = 0; e < 6; ++e) o[2 + e] = g4[e];
            *(bf16x8*)&Gout[gr + 32] = o;
        } else {
            const bf16x8 v4 = ldg(4), v5 = ldg(5), v6 = ldg(6), v7 = ldg(7);
            bf16x8 o;
            o[0] = v4[6]; o[1] = v4[7];
#pragma unroll
            for (int e = 0; e < 6; ++e) o[2 + e] = v5[e];
            *(bf16x8*)&Gout[gr + 40] = o;
            o[0] = v5[6]; o[1] = v5[7];
#pragma unroll
            for (int e = 0; e < 6; ++e) o[2 + e] = v6[e];
            *(bf16x8*)&Gout[gr + 48] = o;
            o[0] = v6[6]; o[1] = v6[7];
#pragma unroll
            for (int e = 0; e < 6; ++e) o[2 + e] = v7[e];
            *(bf16x8*)&Gout[gr + 56] = o;
            o[0] = v7[6]; o[1] = v7[7];
#pragma unroll
            for (int e = 0; e < 6; ++e) o[2 + e] = (__bf16)0.f;
            *(bf16x8*)&Gout[gr + 64] = o;
            // x-cols of secs 1/2: identical to gate's (cats share x); A == Gg
            *(bf16x2*)&Gout[gr + 72]  = *(const bf16x2*)&A[gr + 72];
            *(bf16x2*)&Gout[gr + 144] = *(const bf16x2*)&A[gr + 144];
        }
    }
}

extern "C" void kernel_launch(void* const* d_in, const int* in_sizes, int n_in,
                              void* d_out, int out_size, void* d_ws, size_t ws_size,
                              hipStream_t stream) {
    (void)in_sizes; (void)n_in; (void)out_size; (void)ws_size;
    const float* x  = (const float*)d_in[0];
    const float* st = (const float*)d_in[1];
    const float* E  = (const float*)d_in[2];
    const float* Wg = (const float*)d_in[3];
    const float* bg = (const float*)d_in[4];
    const float* Wu = (const float*)d_in[5];
    const float* bu = (const float*)d_in[6];
    float* out = (float*)d_out;

    char* p = (char*)d_ws;
    __bf16* S   = (__bf16*)p; p += (size_t)2048 * 2048 * 2;   // 8.4 MB
    __bf16* T0  = (__bf16*)p; p += (size_t)2112 * 2048 * 2;   // 8.65 MB (Tu reuses)
    __bf16* T1  = (__bf16*)p; p += (size_t)2112 * 2048 * 2;
    __bf16* Gg  = (__bf16*)p; p += (size_t)65536 * 256 * 2;   // 33.6 MB
    __bf16* Gu  = (__bf16*)p; p += (size_t)65536 * 256 * 2;   // 33.6 MB
    __bf16* ZR  = (__bf16*)p; p += (size_t)65536 * 64 * 2;    // 8.4 MB (r-half only)
    __bf16* WTg = (__bf16*)p; p += 128 * 256 * 2;
    __bf16* WTu = (__bf16*)p; p += 128 * 256 * 2;             // ~101 MB total

    // prologue: S softmax + folded WT packs + gate-cat build (T0, Gg sec0)
    prologue_kernel<<<2816, 256, 0, stream>>>(E, S, Wg, WTg, Wu, WTu, x, st, T0, Gg);

    // gate phase (big GEMMs: 16m x 33c tiles of 128x64, cmode0)
    gemm_pipe<<<528, 256, 0, stream>>>(S, 2048, T0, 2048, 2048, 0, 1, 0, T1, nullptr, nullptr, nullptr, nullptr, Gg, 72);
    gemm_pipe<<<528, 256, 0, stream>>>(S, 2048, T1, 2048, 2048, 1, 1, 0, nullptr, nullptr, nullptr, nullptr, nullptr, Gg, 144);
    // gate W-GEMM, single 128-wide c-pass; fused update-cat build (Tu in T0's buf)
    gemm_w<<<512, 256, 0, stream>>>(Gg, WTg, T0, bg, ZR, st, Gu, x);

    // update phase (packed C=2048: 16m x 32c tiles, cmode1)
    gemm_pipe<<<512, 256, 0, stream>>>(S, 2048, T0, 2048, 2048, 0, 1, 1, T1, nullptr, nullptr, nullptr, nullptr, Gu, 72);
    gemm_pipe<<<512, 256, 0, stream>>>(S, 2048, T1, 2048, 2048, 1, 1, 1, nullptr, nullptr, nullptr, nullptr, nullptr, Gu, 144);
    // update W-GEMM: 64-wide c-pass over WTu rows 0..63
    gemm_pipe<<<dim3(512, 1), 256, 0, stream>>>(Gu, 256, WTu, 256, 256, 3, 0, 0, nullptr, out, bu, ZR, st, nullptr, 0);
}

// Round 7
// 251.111 us; speedup vs baseline: 1.0415x; 1.0415x over previous
//
#include <hip/hip_runtime.h>

// AGCRNCell on gfx950.  B=32, N=2048, C=66, CHEB_K=3, F=2112 (= 33*64, exact).
// R16 = R14 verbatim (verified 252.9 us). R15's LDS-transpose write-granularity
//      experiment REGRESSED (+8.6 us): R14's epilogue store pattern already
//      fully covers every 64B line per block (kq-quads give 32B runs; waves x
//      i-loop complete the lines), so L2 write-combining made the "partial-line
//      RMW" theory moot, and the transpose pass was pure added cost.
//      Structure map (measured): 128x128 tile -> residency collapse (R12,
//      MfmaUtil 13%); 64x64 2-wave -> TLP loss (R9); write restructure -> loss
//      (R15); glue fusions that pay are in (R11/R14). This is the optimum of
//      the explored family.
//      Components: fused prologue (softmax S + folded WT packs + gate-cat
//      build), Chebyshev W-fold (G = [cat|Sx|S^2x], W' = [W0-W2|W1|2W2]),
//      4 big GEMMs on the 128x64 / 528-block / 3-blk-per-CU core,
//      single-pass 128-wide gate W-GEMM with fused update-cat build,
//      64-wide update W-GEMM with fused GRU output epilogue.

typedef __bf16 bf16x8 __attribute__((ext_vector_type(8)));
typedef __bf16 bf16x4 __attribute__((ext_vector_type(4)));
typedef float  f32x4  __attribute__((ext_vector_type(4)));

#define GLB(p) ((__attribute__((address_space(1))) void*)(void*)(p))
#define LDS(p) ((__attribute__((address_space(3))) void*)(p))

// ---- fused prologue ----
// blocks [0,2048):     S[n][m] = softmax_m(relu(E[n]·E[m]))
// blocks [2048,2176):  WTg[o][k] folded: jj0 -> W0-W2, jj1 -> W1, jj2 -> 2*W2
// blocks [2176,2304):  WTu[o][k] folded likewise (rows 64..127 zero)
// blocks [2304,2816):  build gate-cat: T0[f][n] + G_gate sec0  (cat = [x,state])
__global__ __launch_bounds__(256, 2)
void prologue_kernel(const float* __restrict__ E, __bf16* __restrict__ S,
                     const float* __restrict__ Wg, __bf16* __restrict__ WTg,
                     const float* __restrict__ Wu, __bf16* __restrict__ WTu,
                     const float* __restrict__ x, const float* __restrict__ st,
                     __bf16* __restrict__ T, __bf16* __restrict__ G) {
    const int bid = blockIdx.x;
    const int t = threadIdx.x;            // 256
    __shared__ float Ls[66 * 129];        // 34 KB (build branch; [0..7] reused as red)
    if (bid >= 2304) {
        // ---- build gate-cat branch ----
        const int rb = bid - 2304;
        const int b  = rb >> 4;
        const int n0 = (rb & 15) << 7;
        const size_t mb = (size_t)b * 2048 + n0;
        if (t < 128) {
            const float2 v = *(const float2*)&x[(mb + t) * 2];
            Ls[t] = v.x;
            Ls[129 + t] = v.y;
        }
#pragma unroll
        for (int r = 0; r < 8; ++r) {        // 128 rows x 16 col-quads
            const int task = r * 256 + t;
            const int q = task & 15, n = task >> 4;
            f32x4 v = *(const f32x4*)&st[(mb + n) * 64 + q * 4];
            const int base = (2 + q * 4) * 129 + n;
#pragma unroll
            for (int j = 0; j < 4; ++j) Ls[base + j * 129] = v[j];
        }
        __syncthreads();
        // T-layout store: coalesced columns
#pragma unroll
        for (int r = 0; r < 5; ++r) {        // 66 c x 16 segs = 1056 tasks
            const int task = r * 256 + t;
            if (task < 1056) {
                const int c = task >> 4, seg = task & 15;
                const float* src = &Ls[c * 129 + seg * 8];
                bf16x8 o;
#pragma unroll
                for (int j = 0; j < 8; ++j) o[j] = (__bf16)src[j];
                *(bf16x8*)&T[(size_t)(b * 66 + c) * 2048 + n0 + seg * 8] = o;
            }
        }
        // G section 0: row (b, n0+n), k = cc in [0,66), octets 0..8 (cc>=66 -> 0)
        {
            const int n = t & 127, half = t >> 7;
            const size_t grow = ((size_t)(b * 2048 + n0 + n)) * 256;
            for (int oct = half * 5; oct < (half ? 9 : 5); ++oct) {
                bf16x8 o8;
#pragma unroll
                for (int j = 0; j < 8; ++j) {
                    const int cc = oct * 8 + j;
                    o8[j] = (cc < 66) ? (__bf16)Ls[cc * 129 + n] : (__bf16)0.f;
                }
                *(bf16x8*)&G[grow + oct * 8] = o8;
            }
        }
        return;
    }
    if (bid >= 2048) {
        // ---- folded weight-transpose branch ----
        const float* W = (bid < 2176) ? Wg : Wu;
        __bf16* WT = (bid < 2176) ? WTg : WTu;
        const int Nout = (bid < 2176) ? 128 : 64;
        const int id = (bid - ((bid < 2176) ? 2048 : 2176)) * 256 + t;  // 128*256
        const int o = id >> 8, k = id & 255;
        const int jj = (k >= 144) ? 2 : (k >= 72 ? 1 : 0);
        const int cc = k - 72 * jj;
        const bool ok = (o < Nout) && (cc < 66) && (k < 216);
        float v = 0.f;
        if (ok) {
            if (jj == 0)      v = W[(size_t)cc * Nout + o] - W[(size_t)(132 + cc) * Nout + o];
            else if (jj == 1) v = W[(size_t)(66 + cc) * Nout + o];
            else              v = 2.f * W[(size_t)(132 + cc) * Nout + o];
        }
        WT[id] = (__bf16)v;
        return;
    }
    // ---- adaptive-adjacency softmax branch ----
    const int n = bid;
    const int l = t & 63, w = t >> 6;
    float* sm = Ls;           // [0..3]
    float* ss = Ls + 4;       // [4..7]
    float en[10];
#pragma unroll
    for (int i = 0; i < 10; ++i) en[i] = E[n * 10 + i];
    float vals[8];
    float mx = 0.f;
#pragma unroll
    for (int q = 0; q < 8; ++q) {
        const int m = q * 256 + t;
        const float* em = E + (size_t)m * 10;
        float d = 0.f;
#pragma unroll
        for (int i = 0; i < 10; ++i) d += en[i] * em[i];
        d = fmaxf(d, 0.f);
        vals[q] = d;
        mx = fmaxf(mx, d);
    }
#pragma unroll
    for (int off = 32; off; off >>= 1) mx = fmaxf(mx, __shfl_xor(mx, off));
    if (l == 0) sm[w] = mx;
    __syncthreads();
    mx = fmaxf(fmaxf(sm[0], sm[1]), fmaxf(sm[2], sm[3]));
    float sum = 0.f;
#pragma unroll
    for (int q = 0; q < 8; ++q) { vals[q] = __expf(vals[q] - mx); sum += vals[q]; }
#pragma unroll
    for (int off = 32; off; off >>= 1) sum += __shfl_xor(sum, off);
    if (l == 0) ss[w] = sum;
    __syncthreads();
    sum = ss[0] + ss[1] + ss[2] + ss[3];
    const float inv = 1.f / sum;
#pragma unroll
    for (int q = 0; q < 8; ++q) S[(size_t)n * 2048 + q * 256 + t] = (__bf16)(vals[q] * inv);
}

// ---------------- pipelined GEMM: out[M][C] = A[M][K] @ Bt[C][K]^T ----------------
// 256 thr = 4 waves (2m x 2c), tile 128m x 64c, wave-tile 64x32 (4x2 frags), BK=64.
// Double-buffered LDS (48 KB -> 3 blocks/CU); per iter: stage next buf ->
// s_waitcnt vmcnt(6) -> raw s_barrier -> compute -> raw s_barrier. XOR-granule
// swizzle: conflict-free ds_read_b128. swz=1: mt = id&15, ct = id>>4.
// epi: 0 outT[c][m]=bf16(acc), + G sec (gsec=72)
//      1 G sec only (gsec=144), val = bf16(acc)          [W-fold: plain S^2x]
//      3 (c<64) outF[m*64+c] = r*state+(1-r)*tanh(acc+bias[c]), r=zrI[m*64+c]
__global__ __launch_bounds__(256, 3)
void gemm_pipe(const __bf16* __restrict__ A, int lda,
               const __bf16* __restrict__ Bt, int ldb,
               int K, int epi, int swz,
               __bf16* __restrict__ outT,
               float* __restrict__ outF, const float* __restrict__ bias,
               const __bf16* __restrict__ zrI,
               const float* __restrict__ state,
               __bf16* __restrict__ Gout, int gsec) {
    __shared__ __align__(16) __bf16 As[2][128 * 64];   // 32 KB
    __shared__ __align__(16) __bf16 Bs[2][64 * 64];    // 16 KB
    int mt, ct;
    if (swz) { mt = blockIdx.x & 15; ct = blockIdx.x >> 4; }
    else     { mt = blockIdx.x;      ct = blockIdx.y; }
    const int m0 = mt * 128, c0 = ct * 64;
    const int t = threadIdx.x;
    const int l = t & 63, w = t >> 6;
    const int wr = w >> 1, wc = w & 1;
    const int lm = l & 15, kq = l >> 4, lm7 = lm & 7;
    const int sr = l >> 3;               // row-within-chunk
    const int gsw = (l & 7) ^ sr;        // swizzled source granule

    f32x4 acc[4][2];
#pragma unroll
    for (int i = 0; i < 4; ++i)
#pragma unroll
        for (int j = 0; j < 2; ++j) acc[i][j] = (f32x4)0.f;

    const __bf16* Asrc = A  + (size_t)(m0 + w * 8 + sr) * lda + gsw * 8;
    const __bf16* Bsrc = Bt + (size_t)(c0 + w * 8 + sr) * ldb + gsw * 8;
    const int dstA = w * 512 + l * 8;

    auto stage = [&](int buf, int k0) {
#pragma unroll
        for (int q = 0; q < 4; ++q)
            __builtin_amdgcn_global_load_lds(GLB(Asrc + (size_t)q * 32 * lda + k0),
                                             LDS(&As[buf][q * 2048 + dstA]), 16, 0, 0);
#pragma unroll
        for (int q = 0; q < 2; ++q)
            __builtin_amdgcn_global_load_lds(GLB(Bsrc + (size_t)q * 32 * ldb + k0),
                                             LDS(&Bs[buf][q * 2048 + dstA]), 16, 0, 0);
    };
    auto compute = [&](int buf) {
        const __bf16* Ab = &As[buf][0];
        const __bf16* Bb = &Bs[buf][0];
#pragma unroll
        for (int ks = 0; ks < 2; ++ks) {
            const int ga = (((ks << 2) | kq) ^ lm7) << 3;
            bf16x8 af[4], bfr[2];
#pragma unroll
            for (int i = 0; i < 4; ++i)
                af[i] = *(const bf16x8*)&Ab[(wr * 64 + i * 16 + lm) * 64 + ga];
#pragma unroll
            for (int j = 0; j < 2; ++j)
                bfr[j] = *(const bf16x8*)&Bb[(wc * 32 + j * 16 + lm) * 64 + ga];
#pragma unroll
            for (int i = 0; i < 4; ++i)
#pragma unroll
                for (int j = 0; j < 2; ++j)
                    acc[i][j] = __builtin_amdgcn_mfma_f32_16x16x32_bf16(af[i], bfr[j], acc[i][j], 0, 0, 0);
        }
    };

    stage(0, 0);
    const int iters = K >> 6;            // even (32 big / 4 W)
    for (int i = 0; i + 2 <= iters; i += 2) {
        stage(1, (i + 1) << 6);
        __builtin_amdgcn_sched_barrier(0);
        __builtin_amdgcn_s_waitcnt(0x0F76);      // vmcnt(6): own buf0 loads done
        __builtin_amdgcn_s_barrier();
        __builtin_amdgcn_sched_barrier(0);
        compute(0);
        __builtin_amdgcn_sched_barrier(0);
        __builtin_amdgcn_s_barrier();            // buf0 free for restage
        __builtin_amdgcn_sched_barrier(0);
        if (i + 2 < iters) {
            stage(0, (i + 2) << 6);
            __builtin_amdgcn_sched_barrier(0);
            __builtin_amdgcn_s_waitcnt(0x0F76);  // vmcnt(6): own buf1 loads done
        } else {
            __builtin_amdgcn_s_waitcnt(0x0F70);  // vmcnt(0)
        }
        __builtin_amdgcn_s_barrier();
        __builtin_amdgcn_sched_barrier(0);
        compute(1);
        __builtin_amdgcn_sched_barrier(0);
        if (i + 4 <= iters) {
            __builtin_amdgcn_s_barrier();        // buf1 free for restage
            __builtin_amdgcn_sched_barrier(0);
        }
    }

    // epilogue: C row = m (quad*4+reg), col = lane&15  [verified m89 layout]
    const int rb0 = m0 + wr * 64 + kq * 4;
    const int cb0 = c0 + wc * 32 + lm;
#pragma unroll
    for (int i = 0; i < 4; ++i) {
        const int rbase = rb0 + i * 16;
#pragma unroll
        for (int j = 0; j < 2; ++j) {
            const int c = cb0 + j * 16;
            f32x4 v = acc[i][j];
            if (epi <= 1) {
                bf16x4 pk;
#pragma unroll
                for (int r = 0; r < 4; ++r) pk[r] = (__bf16)v[r];
                if (epi == 0)
                    *(bf16x4*)&outT[(size_t)c * 2048 + rbase] = pk;
                // G scatter: row (b, n=rbase+r), k = gsec + cc, b = c/66
                const int b = c / 66, cc = c - b * 66;
                const size_t gb = ((size_t)(b * 2048 + rbase)) * 256 + gsec + cc;
#pragma unroll
                for (int r = 0; r < 4; ++r) Gout[gb + (size_t)r * 256] = pk[r];
            } else {
                if (c < 64) {
                    const float bb = bias[c];
#pragma unroll
                    for (int r = 0; r < 4; ++r) {
                        const int m = rbase + r;
                        float xx = fminf(fmaxf(v[r] + bb, -15.f), 15.f);
                        float e = __expf(2.f * xx);
                        float hc = (e - 1.f) / (e + 1.f);
                        float rr = (float)zrI[(size_t)m * 64 + c];
                        float s = state[(size_t)m * 64 + c];
                        outF[(size_t)m * 64 + c] = rr * s + (1.f - rr) * hc;
                    }
                }
            }
        }
    }
}

// ---------------- wide W-GEMM (gate only): out[M][128] = A[M][256] @ Bt[128][256]^T
// tile 128m x 128c, 4 waves (2x2), wave-tile 64x64 (4x4 frags), BK=64, K=256.
// 64 KB LDS dbuf -> 2 blocks/CU; grid 512 (one c-pass: G fetched ONCE).
// epi (fused gate): c<64 -> z=sigmoid(acc+bias[c]); z*state -> T0 + Gu sec0;
//                   c>=64 -> ZR[m*64+c-64]=sigmoid(acc+bias[c]).
// side section (t<128): x cols 0,1 + zero pads 66..71 of update-cat.
__global__ __launch_bounds__(256, 2)
void gemm_w(const __bf16* __restrict__ A,
            const __bf16* __restrict__ Bt,
            __bf16* __restrict__ outT, const float* __restrict__ bias,
            __bf16* __restrict__ zrO,
            const float* __restrict__ state,
            __bf16* __restrict__ Gout,
            const float* __restrict__ xin) {
    __shared__ __align__(16) __bf16 As[2][128 * 64];   // 32 KB
    __shared__ __align__(16) __bf16 Bs[2][128 * 64];   // 32 KB
    const int m0 = blockIdx.x * 128;
    const int t = threadIdx.x;
    const int l = t & 63, w = t >> 6;
    const int wr = w >> 1, wc = w & 1;
    const int lm = l & 15, kq = l >> 4, lm7 = lm & 7;
    const int sr = l >> 3;
    const int gsw = (l & 7) ^ sr;

    f32x4 acc[4][4];
#pragma unroll
    for (int i = 0; i < 4; ++i)
#pragma unroll
        for (int j = 0; j < 4; ++j) acc[i][j] = (f32x4)0.f;

    const __bf16* Asrc = A  + (size_t)(m0 + w * 8 + sr) * 256 + gsw * 8;
    const __bf16* Bsrc = Bt + (size_t)(w * 8 + sr) * 256 + gsw * 8;
    const int dstA = w * 512 + l * 8;

    auto stage = [&](int buf, int k0) {
#pragma unroll
        for (int q = 0; q < 4; ++q)
            __builtin_amdgcn_global_load_lds(GLB(Asrc + (size_t)q * 32 * 256 + k0),
                                             LDS(&As[buf][q * 2048 + dstA]), 16, 0, 0);
#pragma unroll
        for (int q = 0; q < 4; ++q)
            __builtin_amdgcn_global_load_lds(GLB(Bsrc + (size_t)q * 32 * 256 + k0),
                                             LDS(&Bs[buf][q * 2048 + dstA]), 16, 0, 0);
    };
    auto compute = [&](int buf) {
        const __bf16* Ab = &As[buf][0];
        const __bf16* Bb = &Bs[buf][0];
#pragma unroll
        for (int ks = 0; ks < 2; ++ks) {
            const int ga = (((ks << 2) | kq) ^ lm7) << 3;
            bf16x8 af[4], bfr[4];
#pragma unroll
            for (int i = 0; i < 4; ++i)
                af[i] = *(const bf16x8*)&Ab[(wr * 64 + i * 16 + lm) * 64 + ga];
#pragma unroll
            for (int j = 0; j < 4; ++j)
                bfr[j] = *(const bf16x8*)&Bb[(wc * 64 + j * 16 + lm) * 64 + ga];
#pragma unroll
            for (int i = 0; i < 4; ++i)
#pragma unroll
                for (int j = 0; j < 4; ++j)
                    acc[i][j] = __builtin_amdgcn_mfma_f32_16x16x32_bf16(af[i], bfr[j], acc[i][j], 0, 0, 0);
        }
    };

    stage(0, 0);
    const int iters = 4;                 // K=256, BK=64
    for (int i = 0; i + 2 <= iters; i += 2) {
        stage(1, (i + 1) << 6);
        __builtin_amdgcn_sched_barrier(0);
        __builtin_amdgcn_s_waitcnt(0x0F78);      // vmcnt(8): own buf0 loads done
        __builtin_amdgcn_s_barrier();
        __builtin_amdgcn_sched_barrier(0);
        compute(0);
        __builtin_amdgcn_sched_barrier(0);
        __builtin_amdgcn_s_barrier();            // buf0 free for restage
        __builtin_amdgcn_sched_barrier(0);
        if (i + 2 < iters) {
            stage(0, (i + 2) << 6);
            __builtin_amdgcn_sched_barrier(0);
            __builtin_amdgcn_s_waitcnt(0x0F78);  // vmcnt(8): own buf1 loads done
        } else {
            __builtin_amdgcn_s_waitcnt(0x0F70);  // vmcnt(0)
        }
        __builtin_amdgcn_s_barrier();
        __builtin_amdgcn_sched_barrier(0);
        compute(1);
        __builtin_amdgcn_sched_barrier(0);
        if (i + 4 <= iters) {                    // barrier before next buf1 restage
            __builtin_amdgcn_s_barrier();
            __builtin_amdgcn_sched_barrier(0);
        }
    }

    const int rb0 = m0 + wr * 64 + kq * 4;
    const int cb0 = wc * 64 + lm;
#pragma unroll
    for (int i = 0; i < 4; ++i) {
        const int rbase = rb0 + i * 16;
#pragma unroll
        for (int j = 0; j < 4; ++j) {
            const int c = cb0 + j * 16;
            f32x4 v = acc[i][j];
            const float bb = bias[c];
            if (c < 64) {
                // fused update-cat build: z*state -> T0 row f=b*66+2+c, Gu sec0
                const int b = rbase >> 11, n = rbase & 2047;
                bf16x4 pk;
#pragma unroll
                for (int r = 0; r < 4; ++r) {
                    float xx = fminf(fmaxf(v[r] + bb, -30.f), 30.f);
                    const float z = 1.f / (1.f + __expf(-xx));
                    const float sv = state[(size_t)(rbase + r) * 64 + c];
                    pk[r] = (__bf16)(z * sv);
                    Gout[((size_t)(rbase + r)) * 256 + 2 + c] = pk[r];
                }
                *(bf16x4*)&outT[(size_t)(b * 66 + 2 + c) * 2048 + n] = pk;
            } else {
#pragma unroll
                for (int r = 0; r < 4; ++r) {
                    float xx = fminf(fmaxf(v[r] + bb, -30.f), 30.f);
                    zrO[(size_t)(rbase + r) * 64 + (c - 64)] = (__bf16)(1.f / (1.f + __expf(-xx)));
                }
            }
        }
    }
    // side section: x cols 0,1 + zero pads 66..71 of update-cat
    if (t < 128) {
        const int m = m0 + t;
        const int b = m >> 11, n = m & 2047;
        const float2 vx = *(const float2*)&xin[(size_t)m * 2];
        outT[(size_t)(b * 66) * 2048 + n]     = (__bf16)vx.x;
        outT[(size_t)(b * 66 + 1) * 2048 + n] = (__bf16)vx.y;
        Gout[(size_t)m * 256 + 0] = (__bf16)vx.x;
        Gout[(size_t)m * 256 + 1] = (__bf16)vx.y;
#pragma unroll
        for (int cc = 66; cc < 72; ++cc) Gout[(size_t)m * 256 + cc] = (__bf16)0.f;
    }
}

extern "C" void kernel_launch(void* const* d_in, const int* in_sizes, int n_in,
                              void* d_out, int out_size, void* d_ws, size_t ws_size,
                              hipStream_t stream) {
    (void)in_sizes; (void)n_in; (void)out_size; (void)ws_size;
    const float* x  = (const float*)d_in[0];
    const float* st = (const float*)d_in[1];
    const float* E  = (const float*)d_in[2];
    const float* Wg = (const float*)d_in[3];
    const float* bg = (const float*)d_in[4];
    const float* Wu = (const float*)d_in[5];
    const float* bu = (const float*)d_in[6];
    float* out = (float*)d_out;

    char* p = (char*)d_ws;
    __bf16* S   = (__bf16*)p; p += (size_t)2048 * 2048 * 2;   // 8.4 MB
    __bf16* T0  = (__bf16*)p; p += (size_t)2112 * 2048 * 2;   // 8.65 MB
    __bf16* T1  = (__bf16*)p; p += (size_t)2112 * 2048 * 2;
    __bf16* Gg  = (__bf16*)p; p += (size_t)65536 * 256 * 2;   // 33.6 MB
    __bf16* Gu  = (__bf16*)p; p += (size_t)65536 * 256 * 2;   // 33.6 MB
    __bf16* ZR  = (__bf16*)p; p += (size_t)65536 * 64 * 2;    // 8.4 MB (r-half only)
    __bf16* WTg = (__bf16*)p; p += 128 * 256 * 2;
    __bf16* WTu = (__bf16*)p; p += 128 * 256 * 2;             // ~101 MB total

    // prologue: S softmax + folded WT packs + gate-cat build (T0, Gg sec0)
    prologue_kernel<<<2816, 256, 0, stream>>>(E, S, Wg, WTg, Wu, WTu, x, st, T0, Gg);

    // gate phase (big GEMMs: 16m x 33c tiles of 128x64)
    gemm_pipe<<<528, 256, 0, stream>>>(S, 2048, T0, 2048, 2048, 0, 1, T1, nullptr, nullptr, nullptr, nullptr, Gg, 72);
    gemm_pipe<<<528, 256, 0, stream>>>(S, 2048, T1, 2048, 2048, 1, 1, nullptr, nullptr, nullptr, nullptr, nullptr, Gg, 144);
    // gate W-GEMM, single 128-wide c-pass; fused update-cat build
    gemm_w<<<512, 256, 0, stream>>>(Gg, WTg, T0, bg, ZR, st, Gu, x);

    // update phase
    gemm_pipe<<<528, 256, 0, stream>>>(S, 2048, T0, 2048, 2048, 0, 1, T1, nullptr, nullptr, nullptr, nullptr, Gu, 72);
    gemm_pipe<<<528, 256, 0, stream>>>(S, 2048, T1, 2048, 2048, 1, 1, nullptr, nullptr, nullptr, nullptr, nullptr, Gu, 144);
    // update W-GEMM: 64-wide c-pass over WTu rows 0..63
    gemm_pipe<<<dim3(512, 1), 256, 0, stream>>>(Gu, 256, WTu, 256, 256, 3, 0, nullptr, out, bu, ZR, st, nullptr, 0);
}